// Round 1
// baseline (9.594 us; speedup 1.0000x reference)
//
#include <hip/hip_runtime.h>

// BiasingGateB — mathematically constant output.
//
// Proof that out ≡ 0 for ALL inputs:
//   out = where(sigmoid(score) > 0.8, sel, 0)
//   sigmoid(score) > 0.8  ⟺  score > ln(4) ≈ 1.3863
//   score = max_m <inp/(‖inp‖+ε), pat_m/(‖pat_m‖+ε)>
//   Each normalized factor has norm strictly < 1 (‖v‖/(‖v‖+ε) < 1), so by
//   Cauchy–Schwarz every cosine similarity is < 1. fp32 rounding noise is
//   ~1e-6, vastly smaller than the 0.386 gap to the threshold.
//   Hence sigmoid(score) < sigmoid(1) ≈ 0.7311 < 0.8 always, the `where`
//   predicate is false for every row, and out = zeros([B=64, H=16]).
//
// So the optimal kernel is a zero-fill of d_out. The harness poisons d_out
// with 0xAA before timing and re-validates after replays, so the zero-fill
// must run on every call (it does — single deterministic kernel launch).

__global__ void BiasingGateB_zero_out_kernel(float* __restrict__ out, int n) {
    int i = blockIdx.x * blockDim.x + threadIdx.x;
    if (i < n) out[i] = 0.0f;
}

extern "C" void kernel_launch(void* const* d_in, const int* in_sizes, int n_in,
                              void* d_out, int out_size, void* d_ws, size_t ws_size,
                              hipStream_t stream) {
    (void)d_in; (void)in_sizes; (void)n_in; (void)d_ws; (void)ws_size;
    float* out = (float*)d_out;
    const int block = 256;
    const int grid = (out_size + block - 1) / block;  // out_size = 64*16 = 1024 → 4 blocks
    BiasingGateB_zero_out_kernel<<<grid, block, 0, stream>>>(out, out_size);
}